// Round 1
// baseline (128.863 us; speedup 1.0000x reference)
//
#include <hip/hip_runtime.h>
#include <math.h>

// Problem constants (from reference)
#define DIM 256
#define NQ  512
#define NK  512

// ws layout (float offsets). Total = 525,056 floats = 2.1 MB.
#define WS_A   0                    // A = Q@Wq.T              [NQ][DIM]
#define WS_B   (NQ*DIM)             // B = K@Wk.T + bpost      [NK][DIM]
#define WS_MP  (WS_B + NK*DIM)      // mu_prior                [NK]
#define WS_S   (WS_MP + 512)        // samples                 [NQ][NK]
#define WS_P   (WS_S + NQ*NK)       // KL partials             [256]

// ---------------------------------------------------------------------------
// K1: A = Q@Wq.T ; B = K@Wk.T + bpost ; mu_prior = relu(K@W1p.T+b1p)@w2p + b2p - 0.125
// 8 rows per block, thread = output column. X rows staged in LDS (broadcast
// reads), weight rows gathered straight from L2 (L1 holds the 64 active lines
// per wave across the 4 consecutive d-chunks of each 64B line).
// ---------------------------------------------------------------------------
__global__ __launch_bounds__(256) void k1_precompute(
    const float* __restrict__ Q, const float* __restrict__ Km,
    const float* __restrict__ W1p, const float* __restrict__ b1p,
    const float* __restrict__ w2p, const float* __restrict__ b2p,
    const float* __restrict__ Wpost, const float* __restrict__ bpost,
    float* __restrict__ A, float* __restrict__ B, float* __restrict__ mu_prior)
{
    __shared__ float X_lds[8][DIM];
    __shared__ float red[8][260];     // job-2 row-reduce buffer (pad 260: conflict-free)
    const int tid = threadIdx.x;
    const int bid = blockIdx.x;

    int job, r0, wstride, wcol;
    const float* X;
    const float* W;
    if (bid < 64)       { job = 0; r0 = bid * 8;         X = Q;  W = Wpost; wstride = 2*DIM; wcol = 0;   }
    else if (bid < 128) { job = 1; r0 = (bid - 64) * 8;  X = Km; W = Wpost; wstride = 2*DIM; wcol = DIM; }
    else                { job = 2; r0 = (bid - 128) * 8; X = Km; W = W1p;   wstride = DIM;   wcol = 0;   }

    // stage 8 X rows (coalesced float4)
    #pragma unroll
    for (int i = 0; i < 2; ++i) {
        int f4 = tid * 2 + i;             // 0..511
        int row = f4 >> 6, c4 = f4 & 63;
        *(float4*)&X_lds[row][c4 * 4] = *(const float4*)&X[(r0 + row) * DIM + c4 * 4];
    }
    __syncthreads();

    const float* wrow = W + tid * wstride + wcol;
    float acc[8] = {0.f, 0.f, 0.f, 0.f, 0.f, 0.f, 0.f, 0.f};
    #pragma unroll 4
    for (int d0 = 0; d0 < DIM; d0 += 4) {
        float4 w4 = *(const float4*)&wrow[d0];
        #pragma unroll
        for (int r = 0; r < 8; ++r) {
            float4 x4 = *(const float4*)&X_lds[r][d0];   // pure broadcast: conflict-free
            acc[r] = fmaf(x4.x, w4.x, acc[r]);
            acc[r] = fmaf(x4.y, w4.y, acc[r]);
            acc[r] = fmaf(x4.z, w4.z, acc[r]);
            acc[r] = fmaf(x4.w, w4.w, acc[r]);
        }
    }

    if (job == 0) {
        #pragma unroll
        for (int r = 0; r < 8; ++r) A[(r0 + r) * DIM + tid] = acc[r];
    } else if (job == 1) {
        float bp = bpost[tid];
        #pragma unroll
        for (int r = 0; r < 8; ++r) B[(r0 + r) * DIM + tid] = acc[r] + bp;
    } else {
        float b1 = b1p[tid], w2 = w2p[tid];
        #pragma unroll
        for (int r = 0; r < 8; ++r) red[r][tid] = fmaxf(acc[r] + b1, 0.f) * w2;
        __syncthreads();
        int wid = tid >> 6, lane = tid & 63;
        float b2 = b2p[0];
        #pragma unroll
        for (int rr = 0; rr < 2; ++rr) {
            int r = wid * 2 + rr;
            float v = red[r][lane] + red[r][lane + 64] + red[r][lane + 128] + red[r][lane + 192];
            #pragma unroll
            for (int off = 32; off; off >>= 1) v += __shfl_xor(v, off);
            if (lane == 0) mu_prior[r0 + r] = v + b2 - 0.125f;   // - 0.5*sigma_prior^2
        }
    }
}

// ---------------------------------------------------------------------------
// K2: for each (q,k): latent-dot -> phi/logvar -> KL partial + samples.
// 32x32 tiles (grid 16x16), 2x2 pairs per thread, rows {t, t+16} so b128 LDS
// reads are <=2-way bank aliasing (free). VALU-bound by design.
// ---------------------------------------------------------------------------
__global__ __launch_bounds__(256) void k2_latent(
    const float* __restrict__ A, const float* __restrict__ B,
    const float* __restrict__ mu_prior, const float* __restrict__ eps,
    const float* __restrict__ w_mu, const float* __restrict__ b_mu,
    const float* __restrict__ w_lv, const float* __restrict__ b_lv,
    float* __restrict__ samples, float* __restrict__ partials)
{
    __shared__ float A_lds[32][260];
    __shared__ float B_lds[32][260];
    __shared__ float wm[DIM], wl[DIM];
    __shared__ float wred[4];
    const int tid = threadIdx.x;
    const int bq0 = (blockIdx.x >> 4) * 32;
    const int bk0 = (blockIdx.x & 15) * 32;

    #pragma unroll
    for (int i = 0; i < 8; ++i) {
        int f4 = tid + 256 * i;            // 0..2047
        int row = f4 >> 6, c4 = f4 & 63;
        *(float4*)&A_lds[row][c4 * 4] = *(const float4*)&A[(bq0 + row) * DIM + c4 * 4];
        *(float4*)&B_lds[row][c4 * 4] = *(const float4*)&B[(bk0 + row) * DIM + c4 * 4];
    }
    wm[tid] = w_mu[tid];
    wl[tid] = w_lv[tid];
    __syncthreads();

    const int tq = tid >> 4, tk = tid & 15;
    float p00 = 0, p01 = 0, p10 = 0, p11 = 0;
    float l00 = 0, l01 = 0, l10 = 0, l11 = 0;

    #pragma unroll 2
    for (int d0 = 0; d0 < DIM; d0 += 4) {
        float4 a0 = *(const float4*)&A_lds[tq][d0];
        float4 a1 = *(const float4*)&A_lds[tq + 16][d0];
        float4 b0 = *(const float4*)&B_lds[tk][d0];
        float4 b1 = *(const float4*)&B_lds[tk + 16][d0];
        float4 m4 = *(const float4*)&wm[d0];
        float4 v4 = *(const float4*)&wl[d0];
#define STEP(c) { float r_;                                                      \
        r_ = fmaxf(a0.c + b0.c, 0.f); p00 = fmaf(r_, m4.c, p00); l00 = fmaf(r_, v4.c, l00); \
        r_ = fmaxf(a0.c + b1.c, 0.f); p01 = fmaf(r_, m4.c, p01); l01 = fmaf(r_, v4.c, l01); \
        r_ = fmaxf(a1.c + b0.c, 0.f); p10 = fmaf(r_, m4.c, p10); l10 = fmaf(r_, v4.c, l10); \
        r_ = fmaxf(a1.c + b1.c, 0.f); p11 = fmaf(r_, m4.c, p11); l11 = fmaf(r_, v4.c, l11); }
        STEP(x) STEP(y) STEP(z) STEP(w)
#undef STEP
    }

    const float bmu = b_mu[0], blv = b_lv[0];
    const int qa = bq0 + tq, qb = qa + 16;
    const int ka = bk0 + tk, kb = ka + 16;
    const float mpa = mu_prior[ka], mpb = mu_prior[kb];
    const float C0 = -0.69314718056f - 0.5f;   // log(sigma_prior=0.5) - 0.5
    float kls = 0.f;

#define FINISH(pacc, lacc, q, k, mp) {                       \
        float lv   = (lacc) + blv;                           \
        float phi  = (pacc) + bmu;                           \
        float sig2 = expf(lv);                               \
        float sig  = expf(0.5f * lv);                        \
        float mu   = phi - 0.5f * sig2;                      \
        float dm   = mu - (mp);                              \
        kls += C0 - 0.5f * lv + 2.f * (sig2 + dm * dm);      \
        samples[(q) * NK + (k)] = expf(mu + sig * eps[(q) * NK + (k)]); }

    FINISH(p00, l00, qa, ka, mpa)
    FINISH(p01, l01, qa, kb, mpb)
    FINISH(p10, l10, qb, ka, mpa)
    FINISH(p11, l11, qb, kb, mpb)
#undef FINISH

    #pragma unroll
    for (int off = 32; off; off >>= 1) kls += __shfl_xor(kls, off);
    if ((tid & 63) == 0) wred[tid >> 6] = kls;
    __syncthreads();
    if (tid == 0) partials[blockIdx.x] = wred[0] + wred[1] + wred[2] + wred[3];
}

// ---------------------------------------------------------------------------
// K3: per 2 q-rows: softmax over k, context = weights@V (4-way k-split,
// float4 V loads, LDS combine), fused LayerNorm. Block 0 finalizes KL.
// ---------------------------------------------------------------------------
__global__ __launch_bounds__(256) void k3_output(
    const float* __restrict__ samples, const float* __restrict__ V,
    const float* __restrict__ gamma, const float* __restrict__ beta,
    const float* __restrict__ partials, float* __restrict__ out)
{
    __shared__ float w_lds[2][NK];       // unnormalized softmax numerators
    __shared__ float redbuf[8][DIM];     // [ksplit*2 + row][col]
    __shared__ float sred[4], sred2[4], klr[4];
    const int tid = threadIdx.x;
    const int q0 = blockIdx.x * 2;

    if (blockIdx.x == 0) {               // KL finalize (partials ready: stream order)
        float v = partials[tid];
        #pragma unroll
        for (int off = 32; off; off >>= 1) v += __shfl_xor(v, off);
        if ((tid & 63) == 0) klr[tid >> 6] = v;
        __syncthreads();
        if (tid == 0) out[NQ * DIM] = (klr[0] + klr[1] + klr[2] + klr[3]) * (1.f / (float)(NQ * NK));
    }

    float inv[2];
    #pragma unroll
    for (int r = 0; r < 2; ++r) {
        float s0 = samples[(q0 + r) * NK + tid];
        float s1 = samples[(q0 + r) * NK + tid + 256];
        float m = fmaxf(s0, s1);
        #pragma unroll
        for (int off = 32; off; off >>= 1) m = fmaxf(m, __shfl_xor(m, off));
        if ((tid & 63) == 0) sred[tid >> 6] = m;
        __syncthreads();
        m = fmaxf(fmaxf(sred[0], sred[1]), fmaxf(sred[2], sred[3]));
        float e0 = expf(s0 - m), e1 = expf(s1 - m);
        w_lds[r][tid] = e0;
        w_lds[r][tid + 256] = e1;
        float sum = e0 + e1;
        #pragma unroll
        for (int off = 32; off; off >>= 1) sum += __shfl_xor(sum, off);
        __syncthreads();                 // protect sred before reuse
        if ((tid & 63) == 0) sred[tid >> 6] = sum;
        __syncthreads();
        sum = sred[0] + sred[1] + sred[2] + sred[3];
        inv[r] = 1.f / sum;
        __syncthreads();                 // protect sred for next r / LN phase
    }

    // context: thread -> (colgroup g: 4 cols, ksplit s: 128 k's)
    const int g = tid & 63, s = tid >> 6;
    float a00 = 0, a01 = 0, a02 = 0, a03 = 0;
    float a10 = 0, a11 = 0, a12 = 0, a13 = 0;
    const float* vp = V + s * 128 * DIM + 4 * g;
    #pragma unroll 4
    for (int i = 0; i < 128; ++i) {
        float4 v4 = *(const float4*)(vp + i * DIM);   // 64 lanes x 16B contiguous
        int k = s * 128 + i;
        float w0 = w_lds[0][k], w1 = w_lds[1][k];     // wave-uniform broadcast
        a00 = fmaf(w0, v4.x, a00); a01 = fmaf(w0, v4.y, a01);
        a02 = fmaf(w0, v4.z, a02); a03 = fmaf(w0, v4.w, a03);
        a10 = fmaf(w1, v4.x, a10); a11 = fmaf(w1, v4.y, a11);
        a12 = fmaf(w1, v4.z, a12); a13 = fmaf(w1, v4.w, a13);
    }
    *(float4*)&redbuf[s * 2 + 0][4 * g] = make_float4(a00, a01, a02, a03);
    *(float4*)&redbuf[s * 2 + 1][4 * g] = make_float4(a10, a11, a12, a13);
    __syncthreads();

    const float gm = gamma[tid], bt = beta[tid];
    #pragma unroll
    for (int r = 0; r < 2; ++r) {
        float c = redbuf[0 + r][tid] + redbuf[2 + r][tid] + redbuf[4 + r][tid] + redbuf[6 + r][tid];
        c *= inv[r];
        float s1v = c, s2v = c * c;
        #pragma unroll
        for (int off = 32; off; off >>= 1) {
            s1v += __shfl_xor(s1v, off);
            s2v += __shfl_xor(s2v, off);
        }
        if ((tid & 63) == 0) { sred[tid >> 6] = s1v; sred2[tid >> 6] = s2v; }
        __syncthreads();
        float mean = (sred[0] + sred[1] + sred[2] + sred[3]) * (1.f / DIM);
        float msq  = (sred2[0] + sred2[1] + sred2[2] + sred2[3]) * (1.f / DIM);
        float var  = msq - mean * mean;
        float o = (c - mean) / sqrtf(var + 1e-5f) * gm + bt;
        out[(q0 + r) * DIM + tid] = o;
        __syncthreads();
    }
}

// ---------------------------------------------------------------------------
extern "C" void kernel_launch(void* const* d_in, const int* in_sizes, int n_in,
                              void* d_out, int out_size, void* d_ws, size_t ws_size,
                              hipStream_t stream)
{
    (void)in_sizes; (void)n_in; (void)out_size; (void)ws_size;
    const float* Q     = (const float*)d_in[0];
    const float* K     = (const float*)d_in[1];
    const float* V     = (const float*)d_in[2];
    const float* eps   = (const float*)d_in[3];
    const float* W1p   = (const float*)d_in[4];
    const float* b1p   = (const float*)d_in[5];
    const float* w2p   = (const float*)d_in[6];
    const float* b2p   = (const float*)d_in[7];
    const float* Wpost = (const float*)d_in[8];
    const float* bpost = (const float*)d_in[9];
    const float* w_mu  = (const float*)d_in[10];
    const float* b_mu  = (const float*)d_in[11];
    const float* w_lv  = (const float*)d_in[12];
    const float* b_lv  = (const float*)d_in[13];
    const float* gamma = (const float*)d_in[14];
    const float* beta  = (const float*)d_in[15];
    float* out = (float*)d_out;
    float* wsf = (float*)d_ws;

    float* A        = wsf + WS_A;
    float* B        = wsf + WS_B;
    float* mu_prior = wsf + WS_MP;
    float* samples  = wsf + WS_S;
    float* partials = wsf + WS_P;

    k1_precompute<<<dim3(192), dim3(256), 0, stream>>>(
        Q, K, W1p, b1p, w2p, b2p, Wpost, bpost, A, B, mu_prior);
    k2_latent<<<dim3(256), dim3(256), 0, stream>>>(
        A, B, mu_prior, eps, w_mu, b_mu, w_lv, b_lv, samples, partials);
    k3_output<<<dim3(256), dim3(256), 0, stream>>>(
        samples, V, gamma, beta, partials, out);
}

// Round 2
// 123.210 us; speedup vs baseline: 1.0459x; 1.0459x over previous
//
#include <hip/hip_runtime.h>
#include <math.h>

// Problem constants (from reference)
#define DIM 256
#define NQ  512
#define NK  512

// ws layout (float offsets). Total ~2.1 MB (ws is 256 MB, plenty).
#define WS_A   0                    // A = Q@Wq.T              [NQ][DIM]
#define WS_B   (NQ*DIM)             // B = K@Wk.T + bpost      [NK][DIM]
#define WS_MP  (WS_B + NK*DIM)      // mu_prior                [NK]
#define WS_S   (WS_MP + 512)        // samples                 [NQ][NK]
#define WS_P   (WS_S + NQ*NK)       // KL partials             [256]

// ---------------------------------------------------------------------------
// K1: A = Q@Wq.T ; B = K@Wk.T + bpost ; mu_prior = relu(K@W1p.T+b1p)@w2p + b2p - 0.125
// 384 blocks x 512 threads, 4 rows/block, d-dimension halved across thread
// halves (32-iter inner loop -> short critical path), LDS combine.
// ---------------------------------------------------------------------------
__global__ __launch_bounds__(512) void k1_precompute(
    const float* __restrict__ Q, const float* __restrict__ Km,
    const float* __restrict__ W1p, const float* __restrict__ b1p,
    const float* __restrict__ w2p, const float* __restrict__ b2p,
    const float* __restrict__ Wpost, const float* __restrict__ bpost,
    float* __restrict__ A, float* __restrict__ B, float* __restrict__ mu_prior)
{
    __shared__ float X_lds[4][DIM];      // 4 KB
    __shared__ float red[2][4][260];     // 8.3 KB, c-stride 1 -> conflict-free
    const int tid = threadIdx.x;
    const int bid = blockIdx.x;

    const int job = bid >> 7;            // 0..2, 128 blocks each
    const int r0  = (bid & 127) * 4;
    const float* X = (job == 0) ? Q : Km;
    const float* W = (job == 2) ? W1p : Wpost;
    const int wstride = (job == 2) ? DIM : 2 * DIM;
    const int wcol    = (job == 1) ? DIM : 0;

    if (tid < 256) {                     // stage 4 X rows (coalesced float4)
        int row = tid >> 6, c4 = tid & 63;
        *(float4*)&X_lds[row][c4 * 4] = *(const float4*)&X[(r0 + row) * DIM + c4 * 4];
    }
    __syncthreads();

    const int c  = tid & 255;
    const int dh = tid >> 8;             // 0/1: which 128-wide d-half
    const float* wrow = W + c * wstride + wcol + dh * 128;
    const float* xrow0 = &X_lds[0][dh * 128];

    float acc0 = 0.f, acc1 = 0.f, acc2 = 0.f, acc3 = 0.f;
    #pragma unroll 8
    for (int d0 = 0; d0 < 128; d0 += 4) {
        float4 w4 = *(const float4*)&wrow[d0];
        float4 x0 = *(const float4*)&xrow0[d0];
        float4 x1 = *(const float4*)&xrow0[DIM + d0];
        float4 x2 = *(const float4*)&xrow0[2 * DIM + d0];
        float4 x3 = *(const float4*)&xrow0[3 * DIM + d0];
        acc0 = fmaf(x0.x, w4.x, acc0); acc0 = fmaf(x0.y, w4.y, acc0);
        acc0 = fmaf(x0.z, w4.z, acc0); acc0 = fmaf(x0.w, w4.w, acc0);
        acc1 = fmaf(x1.x, w4.x, acc1); acc1 = fmaf(x1.y, w4.y, acc1);
        acc1 = fmaf(x1.z, w4.z, acc1); acc1 = fmaf(x1.w, w4.w, acc1);
        acc2 = fmaf(x2.x, w4.x, acc2); acc2 = fmaf(x2.y, w4.y, acc2);
        acc2 = fmaf(x2.z, w4.z, acc2); acc2 = fmaf(x2.w, w4.w, acc2);
        acc3 = fmaf(x3.x, w4.x, acc3); acc3 = fmaf(x3.y, w4.y, acc3);
        acc3 = fmaf(x3.z, w4.z, acc3); acc3 = fmaf(x3.w, w4.w, acc3);
    }
    red[dh][0][c] = acc0; red[dh][1][c] = acc1;
    red[dh][2][c] = acc2; red[dh][3][c] = acc3;
    __syncthreads();

    if (job < 2) {
        if (tid < 256) {
            #pragma unroll
            for (int r = 0; r < 4; ++r) {
                float v = red[0][r][c] + red[1][r][c];
                if (job == 0) A[(r0 + r) * DIM + c] = v;
                else          B[(r0 + r) * DIM + c] = v + bpost[c];
            }
        }
    } else {
        if (tid < 256) {
            float b1 = b1p[c], w2 = w2p[c];
            #pragma unroll
            for (int r = 0; r < 4; ++r)
                red[0][r][c] = fmaxf(red[0][r][c] + red[1][r][c] + b1, 0.f) * w2;
        }
        __syncthreads();
        int w = tid >> 6, lane = tid & 63;
        if (w < 4) {
            float v = red[0][w][lane] + red[0][w][lane + 64]
                    + red[0][w][lane + 128] + red[0][w][lane + 192];
            #pragma unroll
            for (int off = 32; off; off >>= 1) v += __shfl_xor(v, off);
            if (lane == 0) mu_prior[r0 + w] = v + b2p[0] - 0.125f;
        }
    }
}

// ---------------------------------------------------------------------------
// K2: per (q,k): latent-dot -> phi/logvar -> KL partial + samples.
// 256 blocks x 512 threads: 32x32 tile, 2x2 pairs/thread, d-SPLIT across the
// two thread halves (32-iter inner loop) + LDS combine. 8 waves/CU.
// ---------------------------------------------------------------------------
__global__ __launch_bounds__(512) void k2_latent(
    const float* __restrict__ A, const float* __restrict__ B,
    const float* __restrict__ mu_prior, const float* __restrict__ eps,
    const float* __restrict__ w_mu, const float* __restrict__ b_mu,
    const float* __restrict__ w_lv, const float* __restrict__ b_lv,
    float* __restrict__ samples, float* __restrict__ partials)
{
    __shared__ float A_lds[32][260];     // 33.3 KB
    __shared__ float B_lds[32][260];     // 33.3 KB
    __shared__ float wm[DIM], wl[DIM];   // 2 KB
    __shared__ float red[2][256][9];     // 18.4 KB, stride 9 -> conflict-free
    __shared__ float wred[8];
    const int tid = threadIdx.x;
    const int bq0 = (blockIdx.x >> 4) * 32;
    const int bk0 = (blockIdx.x & 15) * 32;

    #pragma unroll
    for (int i = 0; i < 4; ++i) {
        int f4 = tid + 512 * i;          // 0..2047
        int row = f4 >> 6, c4 = f4 & 63;
        *(float4*)&A_lds[row][c4 * 4] = *(const float4*)&A[(bq0 + row) * DIM + c4 * 4];
        *(float4*)&B_lds[row][c4 * 4] = *(const float4*)&B[(bk0 + row) * DIM + c4 * 4];
    }
    if (tid < 256) { wm[tid] = w_mu[tid]; wl[tid] = w_lv[tid]; }
    __syncthreads();

    const int l  = tid & 255;
    const int dh = tid >> 8;             // d-half
    const int tq = l >> 4, tk = l & 15;
    const int db = dh * 128;

    float p00 = 0, p01 = 0, p10 = 0, p11 = 0;
    float l00 = 0, l01 = 0, l10 = 0, l11 = 0;

    #pragma unroll 4
    for (int dd = 0; dd < 128; dd += 4) {
        int d0 = db + dd;
        float4 a0 = *(const float4*)&A_lds[tq][d0];
        float4 a1 = *(const float4*)&A_lds[tq + 16][d0];
        float4 b0 = *(const float4*)&B_lds[tk][d0];
        float4 b1 = *(const float4*)&B_lds[tk + 16][d0];
        float4 m4 = *(const float4*)&wm[d0];
        float4 v4 = *(const float4*)&wl[d0];
#define STEP(c) { float r_;                                                      \
        r_ = fmaxf(a0.c + b0.c, 0.f); p00 = fmaf(r_, m4.c, p00); l00 = fmaf(r_, v4.c, l00); \
        r_ = fmaxf(a0.c + b1.c, 0.f); p01 = fmaf(r_, m4.c, p01); l01 = fmaf(r_, v4.c, l01); \
        r_ = fmaxf(a1.c + b0.c, 0.f); p10 = fmaf(r_, m4.c, p10); l10 = fmaf(r_, v4.c, l10); \
        r_ = fmaxf(a1.c + b1.c, 0.f); p11 = fmaf(r_, m4.c, p11); l11 = fmaf(r_, v4.c, l11); }
        STEP(x) STEP(y) STEP(z) STEP(w)
#undef STEP
    }

    red[dh][l][0] = p00; red[dh][l][1] = l00;
    red[dh][l][2] = p01; red[dh][l][3] = l01;
    red[dh][l][4] = p10; red[dh][l][5] = l10;
    red[dh][l][6] = p11; red[dh][l][7] = l11;
    __syncthreads();

    float kls = 0.f;
    if (tid < 256) {
        const float bmu = b_mu[0], blv = b_lv[0];
        const int qa = bq0 + tq, qb = qa + 16;
        const int ka = bk0 + tk, kb = ka + 16;
        const float mpa = mu_prior[ka], mpb = mu_prior[kb];
        const float C0 = -0.69314718056f - 0.5f;   // log(sigma_prior) - 0.5

#define FINISH(i, q, k, mp) {                                        \
        float pacc = red[0][tid][2*(i)]   + red[1][tid][2*(i)];      \
        float lacc = red[0][tid][2*(i)+1] + red[1][tid][2*(i)+1];    \
        float lv   = lacc + blv;                                     \
        float phi  = pacc + bmu;                                     \
        float sig  = __expf(0.5f * lv);                              \
        float sig2 = sig * sig;                                      \
        float mu   = phi - 0.5f * sig2;                              \
        float dm   = mu - (mp);                                      \
        kls += C0 - 0.5f * lv + 2.f * (sig2 + dm * dm);              \
        samples[(q) * NK + (k)] = __expf(mu + sig * eps[(q) * NK + (k)]); }

        FINISH(0, qa, ka, mpa)
        FINISH(1, qa, kb, mpb)
        FINISH(2, qb, ka, mpa)
        FINISH(3, qb, kb, mpb)
#undef FINISH
    }

    #pragma unroll
    for (int off = 32; off; off >>= 1) kls += __shfl_xor(kls, off);
    if ((tid & 63) == 0) wred[tid >> 6] = kls;
    __syncthreads();
    if (tid == 0) {
        float s = 0.f;
        #pragma unroll
        for (int i = 0; i < 8; ++i) s += wred[i];
        partials[blockIdx.x] = s;
    }
}

// ---------------------------------------------------------------------------
// K3: per 2 q-rows: softmax over 512 k (one lane each), context = weights@V
// with 8-way k-split (64-iter loop, float4 V loads), fused LayerNorm.
// Block 0 additionally finalizes KL. 512 threads -> 8 waves/CU.
// ---------------------------------------------------------------------------
__global__ __launch_bounds__(512) void k3_output(
    const float* __restrict__ samples, const float* __restrict__ V,
    const float* __restrict__ gamma, const float* __restrict__ beta,
    const float* __restrict__ partials, float* __restrict__ out)
{
    __shared__ float w_lds[2][NK];       // 4 KB
    __shared__ float redbuf[16][DIM];    // 16 KB
    __shared__ float sred[8], sred2[8], klr[8], sinv[2];
    const int tid = threadIdx.x;
    const int q0 = blockIdx.x * 2;

    if (blockIdx.x == 0) {               // KL finalize (partials ready: stream order)
        float v = (tid < 256) ? partials[tid] : 0.f;
        #pragma unroll
        for (int off = 32; off; off >>= 1) v += __shfl_xor(v, off);
        if ((tid & 63) == 0) klr[tid >> 6] = v;
        __syncthreads();
        if (tid == 0) {
            float s = 0.f;
            #pragma unroll
            for (int i = 0; i < 8; ++i) s += klr[i];
            out[NQ * DIM] = s * (1.f / (float)(NQ * NK));
        }
    }

    #pragma unroll
    for (int r = 0; r < 2; ++r) {
        float sv = samples[(q0 + r) * NK + tid];
        float m = sv;
        #pragma unroll
        for (int off = 32; off; off >>= 1) m = fmaxf(m, __shfl_xor(m, off));
        if ((tid & 63) == 0) sred[tid >> 6] = m;
        __syncthreads();
        m = fmaxf(fmaxf(fmaxf(sred[0], sred[1]), fmaxf(sred[2], sred[3])),
                  fmaxf(fmaxf(sred[4], sred[5]), fmaxf(sred[6], sred[7])));
        float e = __expf(sv - m);
        w_lds[r][tid] = e;
        float sum = e;
        #pragma unroll
        for (int off = 32; off; off >>= 1) sum += __shfl_xor(sum, off);
        __syncthreads();                 // all sred reads done before overwrite
        if ((tid & 63) == 0) sred[tid >> 6] = sum;
        __syncthreads();
        if (tid == 0) {
            float s = 0.f;
            #pragma unroll
            for (int i = 0; i < 8; ++i) s += sred[i];
            sinv[r] = 1.f / s;
        }
        __syncthreads();                 // sred free for next r; sinv visible
    }

    // context: thread -> (colgroup g: 4 cols, ksplit s: 64 k's)
    const int g = tid & 63, s = tid >> 6;
    float a00 = 0, a01 = 0, a02 = 0, a03 = 0;
    float a10 = 0, a11 = 0, a12 = 0, a13 = 0;
    const float* vp = V + s * 64 * DIM + 4 * g;
    #pragma unroll 8
    for (int i = 0; i < 64; ++i) {
        float4 v4 = *(const float4*)(vp + i * DIM);   // 64 lanes x 16B contiguous
        int k = s * 64 + i;
        float w0 = w_lds[0][k], w1 = w_lds[1][k];     // wave-uniform broadcast
        a00 = fmaf(w0, v4.x, a00); a01 = fmaf(w0, v4.y, a01);
        a02 = fmaf(w0, v4.z, a02); a03 = fmaf(w0, v4.w, a03);
        a10 = fmaf(w1, v4.x, a10); a11 = fmaf(w1, v4.y, a11);
        a12 = fmaf(w1, v4.z, a12); a13 = fmaf(w1, v4.w, a13);
    }
    *(float4*)&redbuf[s * 2 + 0][4 * g] = make_float4(a00, a01, a02, a03);
    *(float4*)&redbuf[s * 2 + 1][4 * g] = make_float4(a10, a11, a12, a13);
    __syncthreads();

    // LN: thread -> (row r = tid>>8, col = tid&255); row r owns waves 4r..4r+3
    const int r = tid >> 8, col = tid & 255;
    float c = 0.f;
    #pragma unroll
    for (int j = 0; j < 8; ++j) c += redbuf[j * 2 + r][col];
    c *= sinv[r];
    float s1v = c, s2v = c * c;
    #pragma unroll
    for (int off = 32; off; off >>= 1) {
        s1v += __shfl_xor(s1v, off);
        s2v += __shfl_xor(s2v, off);
    }
    if ((tid & 63) == 0) { sred[tid >> 6] = s1v; sred2[tid >> 6] = s2v; }
    __syncthreads();
    float mean = (sred[4 * r] + sred[4 * r + 1] + sred[4 * r + 2] + sred[4 * r + 3]) * (1.f / DIM);
    float msq  = (sred2[4 * r] + sred2[4 * r + 1] + sred2[4 * r + 2] + sred2[4 * r + 3]) * (1.f / DIM);
    float var  = msq - mean * mean;
    out[(q0 + r) * DIM + col] = (c - mean) * rsqrtf(var + 1e-5f) * gamma[col] + beta[col];
}

// ---------------------------------------------------------------------------
extern "C" void kernel_launch(void* const* d_in, const int* in_sizes, int n_in,
                              void* d_out, int out_size, void* d_ws, size_t ws_size,
                              hipStream_t stream)
{
    (void)in_sizes; (void)n_in; (void)out_size; (void)ws_size;
    const float* Q     = (const float*)d_in[0];
    const float* K     = (const float*)d_in[1];
    const float* V     = (const float*)d_in[2];
    const float* eps   = (const float*)d_in[3];
    const float* W1p   = (const float*)d_in[4];
    const float* b1p   = (const float*)d_in[5];
    const float* w2p   = (const float*)d_in[6];
    const float* b2p   = (const float*)d_in[7];
    const float* Wpost = (const float*)d_in[8];
    const float* bpost = (const float*)d_in[9];
    const float* w_mu  = (const float*)d_in[10];
    const float* b_mu  = (const float*)d_in[11];
    const float* w_lv  = (const float*)d_in[12];
    const float* b_lv  = (const float*)d_in[13];
    const float* gamma = (const float*)d_in[14];
    const float* beta  = (const float*)d_in[15];
    float* out = (float*)d_out;
    float* wsf = (float*)d_ws;

    float* A        = wsf + WS_A;
    float* B        = wsf + WS_B;
    float* mu_prior = wsf + WS_MP;
    float* samples  = wsf + WS_S;
    float* partials = wsf + WS_P;

    k1_precompute<<<dim3(384), dim3(512), 0, stream>>>(
        Q, K, W1p, b1p, w2p, b2p, Wpost, bpost, A, B, mu_prior);
    k2_latent<<<dim3(256), dim3(512), 0, stream>>>(
        A, B, mu_prior, eps, w_mu, b_mu, w_lv, b_lv, samples, partials);
    k3_output<<<dim3(256), dim3(512), 0, stream>>>(
        samples, V, gamma, beta, partials, out);
}